// Round 7
// baseline (771.464 us; speedup 1.0000x reference)
//
#include <hip/hip_runtime.h>
#include <cstdint>

#define NA 65536
#define NB 262144
#define MAXNB 6
#define H 256
#define BF 147
#define AF 133
#define NM 2048

typedef unsigned int u32;
typedef __attribute__((ext_vector_type(8))) short bf16x8;
typedef __attribute__((ext_vector_type(4))) float f32x4;

// bf16 helpers (manual, RNE)
__device__ __forceinline__ u32 pack_bf2(float a, float b) {
    u32 ua = __float_as_uint(a); ua = (ua + 0x7FFFu + ((ua >> 16) & 1u)) >> 16;
    u32 ub = __float_as_uint(b); ub = (ub + 0x7FFFu + ((ub >> 16) & 1u)) >> 16;
    return ua | (ub << 16);
}
__device__ __forceinline__ unsigned short bf1(float a) {
    u32 ua = __float_as_uint(a); return (unsigned short)((ua + 0x7FFFu + ((ua >> 16) & 1u)) >> 16);
}
__device__ __forceinline__ float bf_lo(u32 u) { return __uint_as_float(u << 16); }
__device__ __forceinline__ float bf_hi(u32 u) { return __uint_as_float(u & 0xFFFF0000u); }

// ---------------------------------------------------------------------------
// K0: generic weight pack W[K][256] fp32 -> bf16 fragment layout (zero-pad K).
// ---------------------------------------------------------------------------
__global__ __launch_bounds__(256) void k_pack_w(const float* __restrict__ W,
                                                uint4* __restrict__ Wp, int K) {
    int t = blockIdx.x * 256 + threadIdx.x;
    int kbg = t >> 8, col = t & 255;
    int k0 = kbg * 8;
    float x[8];
#pragma unroll
    for (int j = 0; j < 8; ++j)
        x[j] = (k0 + j < K) ? W[(size_t)(k0 + j) * 256 + col] : 0.f;
    uint4 o;
    o.x = pack_bf2(x[0], x[1]); o.y = pack_bf2(x[2], x[3]);
    o.z = pack_bf2(x[4], x[5]); o.w = pack_bf2(x[6], x[7]);
    Wp[t] = o;
}

// ---------------------------------------------------------------------------
// K0b: f_bonds fp32 [NB][147] -> padded bf16 Xp [NB][160] (rows 320B, 64B-aligned)
// ---------------------------------------------------------------------------
__global__ __launch_bounds__(256) void k_prepad(const float* __restrict__ X,
                                                u32* __restrict__ Xp) {
    int t = blockIdx.x * 256 + threadIdx.x;     // [0, NB*40)
    int r = t / 40, c4 = t - r * 40;
    int c = c4 * 4;
    const float* row = X + (size_t)r * BF;
    float v0 = (c + 0 < BF) ? row[c + 0] : 0.f;
    float v1 = (c + 1 < BF) ? row[c + 1] : 0.f;
    float v2 = (c + 2 < BF) ? row[c + 2] : 0.f;
    float v3 = (c + 3 < BF) ? row[c + 3] : 0.f;
    uint2 o; o.x = pack_bf2(v0, v1); o.y = pack_bf2(v2, v3);
    *(uint2*)&Xp[(size_t)r * 80 + c4 * 2] = o;
}

// ---------------------------------------------------------------------------
// K1 (MFMA): inp = Xp(bf16,[NB][160]) @ W_i -> bf16 (pre-act)
// A-fragments direct from global; LDS only for output transpose.
// ---------------------------------------------------------------------------
__global__ __launch_bounds__(256) void k_gemm_wi(const u32* __restrict__ Xp,
                                                 const uint4* __restrict__ Wp,
                                                 u32* __restrict__ outb) {
    __shared__ char xs[64 * 512];  // output transpose only
    const int blk = blockIdx.x;
    const int tid = threadIdx.x;
    const int lane = tid & 63, wv = tid >> 6;
    const int rlo = lane & 15, g = lane >> 4;
    f32x4 acc[4][4] = {};
#pragma unroll
    for (int kb = 0; kb < 5; ++kb) {
        bf16x8 af[4], bfr[4];
#pragma unroll
        for (int rb = 0; rb < 4; ++rb) {
            int row = blk * 64 + rb * 16 + rlo;
            af[rb] = *(const bf16x8*)&Xp[(size_t)row * 80 + (kb * 4 + g) * 4];
        }
#pragma unroll
        for (int cb = 0; cb < 4; ++cb) {
            uint4 w = Wp[(size_t)(kb * 4 + g) * 256 + wv * 64 + cb * 16 + rlo];
            bfr[cb] = *(const bf16x8*)&w;
        }
#pragma unroll
        for (int rb = 0; rb < 4; ++rb)
#pragma unroll
            for (int cb = 0; cb < 4; ++cb)
                acc[rb][cb] = __builtin_amdgcn_mfma_f32_16x16x32_bf16(
                    af[rb], bfr[cb], acc[rb][cb], 0, 0, 0);
    }
#pragma unroll
    for (int rb = 0; rb < 4; ++rb)
#pragma unroll
        for (int cb = 0; cb < 4; ++cb)
#pragma unroll
            for (int r = 0; r < 4; ++r)
                ((unsigned short*)xs)[(rb * 16 + g * 4 + r) * 256 + wv * 64 + cb * 16 + rlo] =
                    bf1(acc[rb][cb][r]);
    __syncthreads();
#pragma unroll
    for (int i = 0; i < 8; ++i) {
        int e = (i * 256 + tid) * 8;
        int row = e >> 8, col = e & 255;
        uint4 dv = *(const uint4*)(xs + row * 512 + col * 2);
        *(uint4*)&outb[(((size_t)blk * 64 + row) * 256 + col) >> 1] = dv;
    }
}

// ---------------------------------------------------------------------------
// K2: aggb[a,:] = sum_j msg(a2b[a][j])[:]  (bf16 in, bf16 out)
// ---------------------------------------------------------------------------
template <bool RELU_SRC>
__global__ __launch_bounds__(256) void k_agg(const u32* __restrict__ msgb,
                                             const int* __restrict__ a2b,
                                             u32* __restrict__ aggb) {
    const int tid = threadIdx.x;
    const int lane = tid & 63, wv = tid >> 6;
    const int a = blockIdx.x * 4 + wv;
    float4 s = {0.f, 0.f, 0.f, 0.f};
#pragma unroll
    for (int j = 0; j < MAXNB; ++j) {
        int b = a2b[a * MAXNB + j];
        uint2 mv = *(const uint2*)&msgb[(size_t)b * 128 + lane * 2];
        float e0 = bf_lo(mv.x), e1 = bf_hi(mv.x), e2 = bf_lo(mv.y), e3 = bf_hi(mv.y);
        if (RELU_SRC) {
            e0 = fmaxf(e0, 0.f); e1 = fmaxf(e1, 0.f);
            e2 = fmaxf(e2, 0.f); e3 = fmaxf(e3, 0.f);
        }
        s.x += e0; s.y += e1; s.z += e2; s.w += e3;
    }
    uint2 o;
    o.x = pack_bf2(s.x, s.y); o.y = pack_bf2(s.z, s.w);
    *(uint2*)&aggb[(size_t)a * 128 + lane * 2] = o;
}

// ---------------------------------------------------------------------------
// K3 (MFMA): msg_out = relu(inp + (agg[b2a] - msg(b2revb)) @ W_m)
// A-fragments built on the fly from DIRECT global gathers (no LDS staging,
// no barriers in main loop). Per (kb,rb): 16 rows x 64B granule gathers;
// 4 waves read same A-data -> L1/L2-served. LDS only for output transpose.
// ---------------------------------------------------------------------------
template <bool RELU_SRC>
__global__ __launch_bounds__(256) void k_msg_update(
    const u32* __restrict__ inpb, const u32* __restrict__ aggb,
    const u32* __restrict__ msgb_in, const int* __restrict__ b2a,
    const int* __restrict__ b2revb, const uint4* __restrict__ Wp,
    u32* __restrict__ msgb_out) {
    __shared__ char xs[64 * 512];  // output transpose only
    const int blk = blockIdx.x;
    const int tid = threadIdx.x;
    const int lane = tid & 63, wv = tid >> 6;
    const int rlo = lane & 15, g = lane >> 4;

    // per-lane gather row indices (16 rows per rb, 4x broadcast over g)
    size_t aRow[4], rRow[4];
#pragma unroll
    for (int rb = 0; rb < 4; ++rb) {
        int b = blk * 64 + rb * 16 + rlo;
        aRow[rb] = (size_t)b2a[b] * 128;
        rRow[rb] = (size_t)b2revb[b] * 128;
    }

    f32x4 acc[4][4] = {};
#pragma unroll 4
    for (int kb = 0; kb < 8; ++kb) {
        const int c16 = kb * 4 + g;  // 16B chunk index within row (0..31)
        bf16x8 af[4], bfr[4];
#pragma unroll
        for (int rb = 0; rb < 4; ++rb) {
            uint4 ga = *(const uint4*)&aggb[aRow[rb] + c16 * 4];
            uint4 gm = *(const uint4*)&msgb_in[rRow[rb] + c16 * 4];
            float a0 = bf_lo(ga.x), a1 = bf_hi(ga.x), a2 = bf_lo(ga.y), a3 = bf_hi(ga.y);
            float a4 = bf_lo(ga.z), a5 = bf_hi(ga.z), a6 = bf_lo(ga.w), a7 = bf_hi(ga.w);
            float m0 = bf_lo(gm.x), m1 = bf_hi(gm.x), m2 = bf_lo(gm.y), m3 = bf_hi(gm.y);
            float m4 = bf_lo(gm.z), m5 = bf_hi(gm.z), m6 = bf_lo(gm.w), m7 = bf_hi(gm.w);
            if (RELU_SRC) {
                m0 = fmaxf(m0, 0.f); m1 = fmaxf(m1, 0.f);
                m2 = fmaxf(m2, 0.f); m3 = fmaxf(m3, 0.f);
                m4 = fmaxf(m4, 0.f); m5 = fmaxf(m5, 0.f);
                m6 = fmaxf(m6, 0.f); m7 = fmaxf(m7, 0.f);
            }
            uint4 pv;
            pv.x = pack_bf2(a0 - m0, a1 - m1);
            pv.y = pack_bf2(a2 - m2, a3 - m3);
            pv.z = pack_bf2(a4 - m4, a5 - m5);
            pv.w = pack_bf2(a6 - m6, a7 - m7);
            af[rb] = *(const bf16x8*)&pv;
        }
#pragma unroll
        for (int cb = 0; cb < 4; ++cb) {
            uint4 w = Wp[(size_t)c16 * 256 + wv * 64 + cb * 16 + rlo];
            bfr[cb] = *(const bf16x8*)&w;
        }
#pragma unroll
        for (int rb = 0; rb < 4; ++rb)
#pragma unroll
            for (int cb = 0; cb < 4; ++cb)
                acc[rb][cb] = __builtin_amdgcn_mfma_f32_16x16x32_bf16(
                    af[rb], bfr[cb], acc[rb][cb], 0, 0, 0);
    }

    // D -> LDS (bf16, linear [64][256])
#pragma unroll
    for (int rb = 0; rb < 4; ++rb)
#pragma unroll
        for (int cb = 0; cb < 4; ++cb)
#pragma unroll
            for (int r = 0; r < 4; ++r)
                ((unsigned short*)xs)[(rb * 16 + g * 4 + r) * 256 + wv * 64 + cb * 16 + rlo] =
                    bf1(acc[rb][cb][r]);
    __syncthreads();

    // fused epilogue: out = relu(inp + D), coalesced bf16x8 per thread
#pragma unroll
    for (int i = 0; i < 8; ++i) {
        int e = (i * 256 + tid) * 8;
        int row = e >> 8, col = e & 255;
        uint4 dv = *(const uint4*)(xs + row * 512 + col * 2);
        size_t go = ((size_t)blk * 64 + row) * 256 + col;
        uint4 iv = *(const uint4*)&inpb[go >> 1];
        uint4 ov;
        ov.x = pack_bf2(fmaxf(bf_lo(dv.x) + bf_lo(iv.x), 0.f),
                        fmaxf(bf_hi(dv.x) + bf_hi(iv.x), 0.f));
        ov.y = pack_bf2(fmaxf(bf_lo(dv.y) + bf_lo(iv.y), 0.f),
                        fmaxf(bf_hi(dv.y) + bf_hi(iv.y), 0.f));
        ov.z = pack_bf2(fmaxf(bf_lo(dv.z) + bf_lo(iv.z), 0.f),
                        fmaxf(bf_hi(dv.z) + bf_hi(iv.z), 0.f));
        ov.w = pack_bf2(fmaxf(bf_lo(dv.w) + bf_lo(iv.w), 0.f),
                        fmaxf(bf_hi(dv.w) + bf_hi(iv.w), 0.f));
        *(uint4*)&msgb_out[go >> 1] = ov;
    }
}

// ---------------------------------------------------------------------------
// K4 (MFMA): atom_h = relu([f_atoms | a_message] @ W_a + b_a) -> bf16
// ---------------------------------------------------------------------------
__global__ __launch_bounds__(256) void k_atomh(
    const float* __restrict__ f_atoms, const unsigned short* __restrict__ amsgb,
    const uint4* __restrict__ Wp, const float* __restrict__ ba,
    u32* __restrict__ athb) {
    __shared__ char xs[64 * 848];
    const int blk = blockIdx.x;
    const int tid = threadIdx.x;
    const int lane = tid & 63, wv = tid >> 6;
    const int rlo = lane & 15, g = lane >> 4;
    for (int idx = tid; idx < 64 * 416; idx += 256) {
        int r = idx / 416, c = idx - r * 416;
        int gr = blk * 64 + r;
        float v;
        if (c < AF) v = f_atoms[(size_t)gr * AF + c];
        else if (c < AF + 256) {
            u32 u = amsgb[(size_t)gr * 256 + (c - AF)];
            v = __uint_as_float(u << 16);
        } else v = 0.f;
        *(unsigned short*)(xs + r * 848 + c * 2) = bf1(v);
    }
    __syncthreads();
    f32x4 acc[4][4] = {};
#pragma unroll
    for (int kb = 0; kb < 13; ++kb) {
        bf16x8 af[4], bfr[4];
#pragma unroll
        for (int rb = 0; rb < 4; ++rb) {
            int row = rb * 16 + rlo;
            af[rb] = *(const bf16x8*)(xs + row * 848 + (kb * 4 + g) * 16);
        }
#pragma unroll
        for (int cb = 0; cb < 4; ++cb) {
            uint4 w = Wp[(size_t)(kb * 4 + g) * 256 + wv * 64 + cb * 16 + rlo];
            bfr[cb] = *(const bf16x8*)&w;
        }
#pragma unroll
        for (int rb = 0; rb < 4; ++rb)
#pragma unroll
            for (int cb = 0; cb < 4; ++cb)
                acc[rb][cb] = __builtin_amdgcn_mfma_f32_16x16x32_bf16(
                    af[rb], bfr[cb], acc[rb][cb], 0, 0, 0);
    }
    __syncthreads();
    float bcol[4];
#pragma unroll
    for (int cb = 0; cb < 4; ++cb) bcol[cb] = ba[wv * 64 + cb * 16 + rlo];
#pragma unroll
    for (int rb = 0; rb < 4; ++rb)
#pragma unroll
        for (int cb = 0; cb < 4; ++cb)
#pragma unroll
            for (int r = 0; r < 4; ++r)
                ((unsigned short*)xs)[(rb * 16 + g * 4 + r) * 256 + wv * 64 + cb * 16 + rlo] =
                    bf1(fmaxf(acc[rb][cb][r] + bcol[cb], 0.f));
    __syncthreads();
#pragma unroll
    for (int i = 0; i < 8; ++i) {
        int e = (i * 256 + tid) * 8;
        int row = e >> 8, col = e & 255;
        uint4 dv = *(const uint4*)(xs + row * 512 + col * 2);
        *(uint4*)&athb[(((size_t)blk * 64 + row) * 256 + col) >> 1] = dv;
    }
}

// ---------------------------------------------------------------------------
// K5: per-molecule mean readout (atom_h bf16); mol_index sorted -> bin search.
// ---------------------------------------------------------------------------
__global__ __launch_bounds__(256) void k_readout(const unsigned short* __restrict__ athb,
                                                 const int* __restrict__ mol_index,
                                                 float* __restrict__ out) {
    __shared__ int s_lo, s_hi;
    const int m = blockIdx.x;
    const int tid = threadIdx.x;
    if (tid == 0) {
        int lo = 0, hi = NA;
        while (lo < hi) { int mid = (lo + hi) >> 1; if (mol_index[mid] < m) lo = mid + 1; else hi = mid; }
        s_lo = lo;
        int lo2 = lo, hi2 = NA;
        while (lo2 < hi2) { int mid = (lo2 + hi2) >> 1; if (mol_index[mid] < m + 1) lo2 = mid + 1; else hi2 = mid; }
        s_hi = lo2;
    }
    __syncthreads();
    const int lo = s_lo, hi = s_hi;
    float s = 0.f;
    for (int a = lo; a < hi; ++a) {
        u32 u = athb[(size_t)a * 256 + tid];
        s += __uint_as_float(u << 16);
    }
    float cnt = (float)(hi - lo);
    out[(size_t)m * 256 + tid] = s / fmaxf(cnt, 1.0f);
}

// ---------------------------------------------------------------------------
extern "C" void kernel_launch(void* const* d_in, const int* in_sizes, int n_in,
                              void* d_out, int out_size, void* d_ws, size_t ws_size,
                              hipStream_t stream) {
    const float* f_atoms = (const float*)d_in[0];
    const float* f_bonds = (const float*)d_in[1];
    const float* W_i     = (const float*)d_in[2];
    const float* W_m     = (const float*)d_in[3];
    const float* W_a     = (const float*)d_in[4];
    const float* b_a     = (const float*)d_in[5];
    const int* a2b       = (const int*)d_in[6];
    const int* b2a       = (const int*)d_in[7];
    const int* b2revb    = (const int*)d_in[8];
    const int* mol_index = (const int*)d_in[9];
    float* out = (float*)d_out;

    const size_t SZ_BH2 = (size_t)NB * H * 2;   // 128 MB bf16 message buf
    const size_t SZ_AG2 = (size_t)NA * H * 2;   // 32 MB bf16 agg
    const size_t SZ_WPM = 32 * 256 * 16;
    const size_t SZ_WPI = 20 * 256 * 16;
    const size_t SZ_WPA = 52 * 256 * 16;
    const size_t NEEDED = 3 * SZ_BH2 + SZ_AG2 + SZ_WPM + SZ_WPI + SZ_WPA;  // ~437 MB
    if (ws_size < NEEDED) return;  // diagnostic guard

    char* ws = (char*)d_ws;
    u32* inp    = (u32*)(ws);
    u32* msg1   = (u32*)(ws + SZ_BH2);
    u32* msg2   = (u32*)(ws + 2 * SZ_BH2);
    u32* aggb   = (u32*)(ws + 3 * SZ_BH2);
    uint4* WpM  = (uint4*)(ws + 3 * SZ_BH2 + SZ_AG2);
    uint4* WpI  = (uint4*)(ws + 3 * SZ_BH2 + SZ_AG2 + SZ_WPM);
    uint4* WpA  = (uint4*)(ws + 3 * SZ_BH2 + SZ_AG2 + SZ_WPM + SZ_WPI);
    u32* Xp     = msg1;  // padded bf16 f_bonds; aliases msg1 (dead until step 1)
    u32* athb   = msg1;  // alias msg1 (dead by K4)

    // one-time packs
    k_pack_w<<<32, 256, 0, stream>>>(W_m, WpM, 256);
    k_pack_w<<<20, 256, 0, stream>>>(W_i, WpI, BF);
    k_pack_w<<<52, 256, 0, stream>>>(W_a, WpA, AF + H);
    k_prepad<<<NB * 40 / 256, 256, 0, stream>>>(f_bonds, Xp);

    // inp = f_bonds @ W_i (pre-activation, bf16); message0 = relu(inp) virtual
    k_gemm_wi<<<NB / 64, 256, 0, stream>>>(Xp, WpI, inp);

    // step 1 (overwrites msg1 -> Xp dead exactly here)
    k_agg<true><<<NA / 4, 256, 0, stream>>>(inp, a2b, aggb);
    k_msg_update<true><<<NB / 64, 256, 0, stream>>>(inp, aggb, inp, b2a, b2revb, WpM, msg1);

    // step 2
    k_agg<false><<<NA / 4, 256, 0, stream>>>(msg1, a2b, aggb);
    k_msg_update<false><<<NB / 64, 256, 0, stream>>>(inp, aggb, msg1, b2a, b2revb, WpM, msg2);

    // atom aggregation + W_a + relu
    k_agg<false><<<NA / 4, 256, 0, stream>>>(msg2, a2b, aggb);
    k_atomh<<<NA / 64, 256, 0, stream>>>(f_atoms, (const unsigned short*)aggb, WpA, b_a, athb);

    // per-molecule mean readout
    k_readout<<<NM, 256, 0, stream>>>((const unsigned short*)athb, mol_index, out);
}

// Round 8
// 576.220 us; speedup vs baseline: 1.3388x; 1.3388x over previous
//
#include <hip/hip_runtime.h>
#include <cstdint>

#define NA 65536
#define NB 262144
#define MAXNB 6
#define H 256
#define BF 147
#define AF 133
#define NM 2048

typedef unsigned int u32;
typedef __attribute__((ext_vector_type(8))) short bf16x8;
typedef __attribute__((ext_vector_type(4))) float f32x4;

// bf16 helpers (manual, RNE)
__device__ __forceinline__ u32 pack_bf2(float a, float b) {
    u32 ua = __float_as_uint(a); ua = (ua + 0x7FFFu + ((ua >> 16) & 1u)) >> 16;
    u32 ub = __float_as_uint(b); ub = (ub + 0x7FFFu + ((ub >> 16) & 1u)) >> 16;
    return ua | (ub << 16);
}
__device__ __forceinline__ unsigned short bf1(float a) {
    u32 ua = __float_as_uint(a); return (unsigned short)((ua + 0x7FFFu + ((ua >> 16) & 1u)) >> 16);
}
__device__ __forceinline__ float bf_lo(u32 u) { return __uint_as_float(u << 16); }
__device__ __forceinline__ float bf_hi(u32 u) { return __uint_as_float(u & 0xFFFF0000u); }

// ---------------------------------------------------------------------------
// K0: generic weight pack W[K][256] fp32 -> bf16 fragment layout (zero-pad K).
// ---------------------------------------------------------------------------
__global__ __launch_bounds__(256) void k_pack_w(const float* __restrict__ W,
                                                uint4* __restrict__ Wp, int K) {
    int t = blockIdx.x * 256 + threadIdx.x;
    int kbg = t >> 8, col = t & 255;
    int k0 = kbg * 8;
    float x[8];
#pragma unroll
    for (int j = 0; j < 8; ++j)
        x[j] = (k0 + j < K) ? W[(size_t)(k0 + j) * 256 + col] : 0.f;
    uint4 o;
    o.x = pack_bf2(x[0], x[1]); o.y = pack_bf2(x[2], x[3]);
    o.z = pack_bf2(x[4], x[5]); o.w = pack_bf2(x[6], x[7]);
    Wp[t] = o;
}

// ---------------------------------------------------------------------------
// K0c: W_a pack with 3-col shift: padded col c -> Wa row (c<133: c;
// 136<=c<392: c-3; else zero). Kpad = 416 -> grid 52.
// ---------------------------------------------------------------------------
__global__ __launch_bounds__(256) void k_pack_wa(const float* __restrict__ W,
                                                 uint4* __restrict__ Wp) {
    int t = blockIdx.x * 256 + threadIdx.x;
    int kbg = t >> 8, col = t & 255;
    int k0 = kbg * 8;
    float x[8];
#pragma unroll
    for (int j = 0; j < 8; ++j) {
        int c = k0 + j;
        float v = 0.f;
        if (c < AF) v = W[(size_t)c * 256 + col];
        else if (c >= 136 && c < 392) v = W[(size_t)(c - 3) * 256 + col];
        x[j] = v;
    }
    uint4 o;
    o.x = pack_bf2(x[0], x[1]); o.y = pack_bf2(x[2], x[3]);
    o.z = pack_bf2(x[4], x[5]); o.w = pack_bf2(x[6], x[7]);
    Wp[t] = o;
}

// ---------------------------------------------------------------------------
// K1 (MFMA, fused prepad): inp = f_bonds(fp32)@W_i -> bf16 (pre-act)
// Stage fp32->bf16 into LDS (stride 336B; 84 words%32=20 -> 2-way only),
// K padded 147->160 (5 steps). Output transposed via LDS (union region).
// ---------------------------------------------------------------------------
__global__ __launch_bounds__(256) void k_gemm_wi(const float* __restrict__ X,
                                                 const uint4* __restrict__ Wp,
                                                 u32* __restrict__ outb) {
    __shared__ char xs[64 * 512];  // stage uses 64*336=21504B; transpose 32768B
    const int blk = blockIdx.x;
    const int tid = threadIdx.x;
    const int lane = tid & 63, wv = tid >> 6;
    const int rlo = lane & 15, g = lane >> 4;

    // stage: wave wv handles rows wv, wv+4, ... (16 rows)
    for (int r = wv; r < 64; r += 4) {
        const float* row = X + ((size_t)blk * 64 + r) * BF;
#pragma unroll
        for (int p = 0; p < 2; ++p) {
            int c = p * 128 + lane * 2;
            if (c < 160) {
                float v0 = (c < BF) ? row[c] : 0.f;
                float v1 = (c + 1 < BF) ? row[c + 1] : 0.f;
                *(u32*)(xs + r * 336 + c * 2) = pack_bf2(v0, v1);
            }
        }
    }
    __syncthreads();

    f32x4 acc[4][4] = {};
#pragma unroll
    for (int kb = 0; kb < 5; ++kb) {
        bf16x8 af[4], bfr[4];
#pragma unroll
        for (int rb = 0; rb < 4; ++rb) {
            int row = rb * 16 + rlo;
            af[rb] = *(const bf16x8*)(xs + row * 336 + (kb * 4 + g) * 16);
        }
#pragma unroll
        for (int cb = 0; cb < 4; ++cb) {
            uint4 w = Wp[(size_t)(kb * 4 + g) * 256 + wv * 64 + cb * 16 + rlo];
            bfr[cb] = *(const bf16x8*)&w;
        }
#pragma unroll
        for (int rb = 0; rb < 4; ++rb)
#pragma unroll
            for (int cb = 0; cb < 4; ++cb)
                acc[rb][cb] = __builtin_amdgcn_mfma_f32_16x16x32_bf16(
                    af[rb], bfr[cb], acc[rb][cb], 0, 0, 0);
    }
    __syncthreads();  // stage region dead; reuse for transpose
#pragma unroll
    for (int rb = 0; rb < 4; ++rb)
#pragma unroll
        for (int cb = 0; cb < 4; ++cb)
#pragma unroll
            for (int r = 0; r < 4; ++r)
                ((unsigned short*)xs)[(rb * 16 + g * 4 + r) * 256 + wv * 64 + cb * 16 + rlo] =
                    bf1(acc[rb][cb][r]);
    __syncthreads();
#pragma unroll
    for (int i = 0; i < 8; ++i) {
        int e = (i * 256 + tid) * 8;
        int row = e >> 8, col = e & 255;
        uint4 dv = *(const uint4*)(xs + row * 512 + col * 2);
        *(uint4*)&outb[(((size_t)blk * 64 + row) * 256 + col) >> 1] = dv;
    }
}

// ---------------------------------------------------------------------------
// K2: aggb[a,:] = sum_j msg(a2b[a][j])[:]  (bf16 in, bf16 out)
// ---------------------------------------------------------------------------
template <bool RELU_SRC>
__global__ __launch_bounds__(256) void k_agg(const u32* __restrict__ msgb,
                                             const int* __restrict__ a2b,
                                             u32* __restrict__ aggb) {
    const int tid = threadIdx.x;
    const int lane = tid & 63, wv = tid >> 6;
    const int a = blockIdx.x * 4 + wv;
    float4 s = {0.f, 0.f, 0.f, 0.f};
#pragma unroll
    for (int j = 0; j < MAXNB; ++j) {
        int b = a2b[a * MAXNB + j];
        uint2 mv = *(const uint2*)&msgb[(size_t)b * 128 + lane * 2];
        float e0 = bf_lo(mv.x), e1 = bf_hi(mv.x), e2 = bf_lo(mv.y), e3 = bf_hi(mv.y);
        if (RELU_SRC) {
            e0 = fmaxf(e0, 0.f); e1 = fmaxf(e1, 0.f);
            e2 = fmaxf(e2, 0.f); e3 = fmaxf(e3, 0.f);
        }
        s.x += e0; s.y += e1; s.z += e2; s.w += e3;
    }
    uint2 o;
    o.x = pack_bf2(s.x, s.y); o.y = pack_bf2(s.z, s.w);
    *(uint2*)&aggb[(size_t)a * 128 + lane * 2] = o;
}

// ---------------------------------------------------------------------------
// K3 (MFMA): msg_out = relu(inp + (agg[b2a] - msg(b2revb)) @ W_m)
// R6-proven staged-LDS version (XOR-swizzled A-tile, 133us).
// ---------------------------------------------------------------------------
template <bool RELU_SRC>
__global__ __launch_bounds__(256) void k_msg_update(
    const u32* __restrict__ inpb, const u32* __restrict__ aggb,
    const u32* __restrict__ msgb_in, const int* __restrict__ b2a,
    const int* __restrict__ b2revb, const uint4* __restrict__ Wp,
    u32* __restrict__ msgb_out) {
    __shared__ char xs[64 * 512];  // 32 KB bf16 [64][256]
    const int blk = blockIdx.x;
    const int tid = threadIdx.x;
    const int lane = tid & 63, wv = tid >> 6;
    const int rlo = lane & 15, g = lane >> 4;

    for (int r = wv; r < 64; r += 4) {
        const int b = blk * 64 + r;
        const int a = b2a[b];
        const int rb_ = b2revb[b];
        uint2 gv = *(const uint2*)&aggb[(size_t)a * 128 + lane * 2];
        uint2 mv = *(const uint2*)&msgb_in[(size_t)rb_ * 128 + lane * 2];
        float m0 = bf_lo(mv.x), m1 = bf_hi(mv.x), m2 = bf_lo(mv.y), m3 = bf_hi(mv.y);
        if (RELU_SRC) {
            m0 = fmaxf(m0, 0.f); m1 = fmaxf(m1, 0.f);
            m2 = fmaxf(m2, 0.f); m3 = fmaxf(m3, 0.f);
        }
        uint2 pk;
        pk.x = pack_bf2(bf_lo(gv.x) - m0, bf_hi(gv.x) - m1);
        pk.y = pack_bf2(bf_lo(gv.y) - m2, bf_hi(gv.y) - m3);
        int schunk = (lane >> 1) ^ (r & 7);
        *(uint2*)(xs + r * 512 + (schunk << 4) + (lane & 1) * 8) = pk;
    }
    __syncthreads();

    f32x4 acc[4][4] = {};
#pragma unroll
    for (int kb = 0; kb < 8; ++kb) {
        bf16x8 af[4], bfr[4];
#pragma unroll
        for (int rb = 0; rb < 4; ++rb) {
            int row = rb * 16 + rlo;
            int schunk = (kb * 4 + g) ^ (row & 7);
            af[rb] = *(const bf16x8*)(xs + row * 512 + (schunk << 4));
        }
#pragma unroll
        for (int cb = 0; cb < 4; ++cb) {
            uint4 w = Wp[(size_t)(kb * 4 + g) * 256 + wv * 64 + cb * 16 + rlo];
            bfr[cb] = *(const bf16x8*)&w;
        }
#pragma unroll
        for (int rb = 0; rb < 4; ++rb)
#pragma unroll
            for (int cb = 0; cb < 4; ++cb)
                acc[rb][cb] = __builtin_amdgcn_mfma_f32_16x16x32_bf16(
                    af[rb], bfr[cb], acc[rb][cb], 0, 0, 0);
    }
    __syncthreads();

#pragma unroll
    for (int rb = 0; rb < 4; ++rb)
#pragma unroll
        for (int cb = 0; cb < 4; ++cb)
#pragma unroll
            for (int r = 0; r < 4; ++r)
                ((unsigned short*)xs)[(rb * 16 + g * 4 + r) * 256 + wv * 64 + cb * 16 + rlo] =
                    bf1(acc[rb][cb][r]);
    __syncthreads();

#pragma unroll
    for (int i = 0; i < 8; ++i) {
        int e = (i * 256 + tid) * 8;
        int row = e >> 8, col = e & 255;
        uint4 dv = *(const uint4*)(xs + row * 512 + col * 2);
        size_t go = ((size_t)blk * 64 + row) * 256 + col;
        uint4 iv = *(const uint4*)&inpb[go >> 1];
        uint4 ov;
        ov.x = pack_bf2(fmaxf(bf_lo(dv.x) + bf_lo(iv.x), 0.f),
                        fmaxf(bf_hi(dv.x) + bf_hi(iv.x), 0.f));
        ov.y = pack_bf2(fmaxf(bf_lo(dv.y) + bf_lo(iv.y), 0.f),
                        fmaxf(bf_hi(dv.y) + bf_hi(iv.y), 0.f));
        ov.z = pack_bf2(fmaxf(bf_lo(dv.z) + bf_lo(iv.z), 0.f),
                        fmaxf(bf_hi(dv.z) + bf_hi(iv.z), 0.f));
        ov.w = pack_bf2(fmaxf(bf_lo(dv.w) + bf_lo(iv.w), 0.f),
                        fmaxf(bf_hi(dv.w) + bf_hi(iv.w), 0.f));
        *(uint4*)&msgb_out[go >> 1] = ov;
    }
}

// ---------------------------------------------------------------------------
// K4 (MFMA, fused agg): atom_h = relu([f_atoms | sum_j msg2(a2b)] @ W_a + b_a)
// Staging does the 6-row gather-sum inline (no aggb round trip).
// LDS [64][416] bf16, stride 832B (208w%32=16 -> 2-way only). amsg at col 136.
// ---------------------------------------------------------------------------
__global__ __launch_bounds__(256) void k_atomh(
    const float* __restrict__ f_atoms, const u32* __restrict__ msgb,
    const int* __restrict__ a2b, const uint4* __restrict__ Wp,
    const float* __restrict__ ba, u32* __restrict__ athb) {
    __shared__ char xs[64 * 832];  // 53248B; transpose region (32768B) fits inside
    const int blk = blockIdx.x;
    const int tid = threadIdx.x;
    const int lane = tid & 63, wv = tid >> 6;
    const int rlo = lane & 15, g = lane >> 4;

    for (int r = wv; r < 64; r += 4) {
        const int gr = blk * 64 + r;
        const float* fa = f_atoms + (size_t)gr * AF;
#pragma unroll
        for (int p = 0; p < 2; ++p) {
            int c = p * 128 + lane * 2;
            if (c < 136) {
                float v0 = (c < AF) ? fa[c] : 0.f;
                float v1 = (c + 1 < AF) ? fa[c + 1] : 0.f;
                *(u32*)(xs + r * 832 + c * 2) = pack_bf2(v0, v1);
            }
        }
        // fused agg: 6-row gather-sum of msg2 (bf16) -> cols 136..391
        float s0 = 0.f, s1 = 0.f, s2 = 0.f, s3 = 0.f;
#pragma unroll
        for (int j = 0; j < MAXNB; ++j) {
            int b = a2b[gr * MAXNB + j];
            uint2 mv = *(const uint2*)&msgb[(size_t)b * 128 + lane * 2];
            s0 += bf_lo(mv.x); s1 += bf_hi(mv.x);
            s2 += bf_lo(mv.y); s3 += bf_hi(mv.y);
        }
        uint2 o; o.x = pack_bf2(s0, s1); o.y = pack_bf2(s2, s3);
        *(uint2*)(xs + r * 832 + 272 + lane * 8) = o;
        if (lane < 6) {  // zero pad cols 392..415
            uint2 z = {0u, 0u};
            *(uint2*)(xs + r * 832 + 784 + lane * 8) = z;
        }
    }
    __syncthreads();

    f32x4 acc[4][4] = {};
#pragma unroll
    for (int kb = 0; kb < 13; ++kb) {
        bf16x8 af[4], bfr[4];
#pragma unroll
        for (int rb = 0; rb < 4; ++rb) {
            int row = rb * 16 + rlo;
            af[rb] = *(const bf16x8*)(xs + row * 832 + (kb * 4 + g) * 16);
        }
#pragma unroll
        for (int cb = 0; cb < 4; ++cb) {
            uint4 w = Wp[(size_t)(kb * 4 + g) * 256 + wv * 64 + cb * 16 + rlo];
            bfr[cb] = *(const bf16x8*)&w;
        }
#pragma unroll
        for (int rb = 0; rb < 4; ++rb)
#pragma unroll
            for (int cb = 0; cb < 4; ++cb)
                acc[rb][cb] = __builtin_amdgcn_mfma_f32_16x16x32_bf16(
                    af[rb], bfr[cb], acc[rb][cb], 0, 0, 0);
    }
    __syncthreads();
    float bcol[4];
#pragma unroll
    for (int cb = 0; cb < 4; ++cb) bcol[cb] = ba[wv * 64 + cb * 16 + rlo];
#pragma unroll
    for (int rb = 0; rb < 4; ++rb)
#pragma unroll
        for (int cb = 0; cb < 4; ++cb)
#pragma unroll
            for (int r = 0; r < 4; ++r)
                ((unsigned short*)xs)[(rb * 16 + g * 4 + r) * 256 + wv * 64 + cb * 16 + rlo] =
                    bf1(fmaxf(acc[rb][cb][r] + bcol[cb], 0.f));
    __syncthreads();
#pragma unroll
    for (int i = 0; i < 8; ++i) {
        int e = (i * 256 + tid) * 8;
        int row = e >> 8, col = e & 255;
        uint4 dv = *(const uint4*)(xs + row * 512 + col * 2);
        *(uint4*)&athb[(((size_t)blk * 64 + row) * 256 + col) >> 1] = dv;
    }
}

// ---------------------------------------------------------------------------
// K5: per-molecule mean readout (atom_h bf16); mol_index sorted -> bin search.
// ---------------------------------------------------------------------------
__global__ __launch_bounds__(256) void k_readout(const unsigned short* __restrict__ athb,
                                                 const int* __restrict__ mol_index,
                                                 float* __restrict__ out) {
    __shared__ int s_lo, s_hi;
    const int m = blockIdx.x;
    const int tid = threadIdx.x;
    if (tid == 0) {
        int lo = 0, hi = NA;
        while (lo < hi) { int mid = (lo + hi) >> 1; if (mol_index[mid] < m) lo = mid + 1; else hi = mid; }
        s_lo = lo;
        int lo2 = lo, hi2 = NA;
        while (lo2 < hi2) { int mid = (lo2 + hi2) >> 1; if (mol_index[mid] < m + 1) lo2 = mid + 1; else hi2 = mid; }
        s_hi = lo2;
    }
    __syncthreads();
    const int lo = s_lo, hi = s_hi;
    float s = 0.f;
    for (int a = lo; a < hi; ++a) {
        u32 u = athb[(size_t)a * 256 + tid];
        s += __uint_as_float(u << 16);
    }
    float cnt = (float)(hi - lo);
    out[(size_t)m * 256 + tid] = s / fmaxf(cnt, 1.0f);
}

// ---------------------------------------------------------------------------
extern "C" void kernel_launch(void* const* d_in, const int* in_sizes, int n_in,
                              void* d_out, int out_size, void* d_ws, size_t ws_size,
                              hipStream_t stream) {
    const float* f_atoms = (const float*)d_in[0];
    const float* f_bonds = (const float*)d_in[1];
    const float* W_i     = (const float*)d_in[2];
    const float* W_m     = (const float*)d_in[3];
    const float* W_a     = (const float*)d_in[4];
    const float* b_a     = (const float*)d_in[5];
    const int* a2b       = (const int*)d_in[6];
    const int* b2a       = (const int*)d_in[7];
    const int* b2revb    = (const int*)d_in[8];
    const int* mol_index = (const int*)d_in[9];
    float* out = (float*)d_out;

    const size_t SZ_BH2 = (size_t)NB * H * 2;   // 128 MB bf16 message buf
    const size_t SZ_AG2 = (size_t)NA * H * 2;   // 32 MB bf16 agg
    const size_t SZ_WPM = 32 * 256 * 16;
    const size_t SZ_WPI = 20 * 256 * 16;
    const size_t SZ_WPA = 52 * 256 * 16;
    const size_t NEEDED = 3 * SZ_BH2 + SZ_AG2 + SZ_WPM + SZ_WPI + SZ_WPA;  // ~416 MB
    if (ws_size < NEEDED) return;  // diagnostic guard

    char* ws = (char*)d_ws;
    u32* inp    = (u32*)(ws);
    u32* msg1   = (u32*)(ws + SZ_BH2);
    u32* msg2   = (u32*)(ws + 2 * SZ_BH2);
    u32* aggb   = (u32*)(ws + 3 * SZ_BH2);
    uint4* WpM  = (uint4*)(ws + 3 * SZ_BH2 + SZ_AG2);
    uint4* WpI  = (uint4*)(ws + 3 * SZ_BH2 + SZ_AG2 + SZ_WPM);
    uint4* WpA  = (uint4*)(ws + 3 * SZ_BH2 + SZ_AG2 + SZ_WPM + SZ_WPI);
    u32* athb   = msg1;  // alias msg1 (dead by K4)

    // one-time weight packs
    k_pack_w<<<32, 256, 0, stream>>>(W_m, WpM, 256);
    k_pack_w<<<20, 256, 0, stream>>>(W_i, WpI, BF);
    k_pack_wa<<<52, 256, 0, stream>>>(W_a, WpA);

    // inp = f_bonds @ W_i (pre-activation, bf16); message0 = relu(inp) virtual
    k_gemm_wi<<<NB / 64, 256, 0, stream>>>(f_bonds, WpI, inp);

    // step 1
    k_agg<true><<<NA / 4, 256, 0, stream>>>(inp, a2b, aggb);
    k_msg_update<true><<<NB / 64, 256, 0, stream>>>(inp, aggb, inp, b2a, b2revb, WpM, msg1);

    // step 2
    k_agg<false><<<NA / 4, 256, 0, stream>>>(msg1, a2b, aggb);
    k_msg_update<false><<<NB / 64, 256, 0, stream>>>(inp, aggb, msg1, b2a, b2revb, WpM, msg2);

    // fused atom aggregation + W_a + relu
    k_atomh<<<NA / 64, 256, 0, stream>>>(f_atoms, msg2, a2b, WpA, b_a, athb);

    // per-molecule mean readout
    k_readout<<<NM, 256, 0, stream>>>((const unsigned short*)athb, mol_index, out);
}